// Round 2
// baseline (455.680 us; speedup 1.0000x reference)
//
#include <hip/hip_runtime.h>
#include <stdint.h>
#include <stddef.h>

// Problem constants (fixed by the reference)
#define DDIM   512
#define KCL    1024
#define BK     32
#define KSTEPS (DDIM / BK)          // 16
#define RPB    64                   // rows per block
#define THR    1024                 // threads per block (16 waves)
#define NROWS  65536
#define NBLK   (NROWS / RPB)        // 1024

// A panel in LDS: 64 rows x 512 halves, row padded 512->520 halves (1040 B)
// pad makes frag ds_read_b128 bank-shift 4/row -> max 2-way (free, m136)
#define SA_STRIDE_H 520
#define SA_ROW_B    (SA_STRIDE_H * 2)           // 1040
#define SA_BYTES    (RPB * SA_ROW_B)            // 66560
#define SMEM_BYTES  (SA_BYTES + 512)            // 67072 (<160 KiB; also <2/CU but regs cap us anyway)

typedef __attribute__((ext_vector_type(4))) float    floatx4;
typedef __attribute__((ext_vector_type(8))) _Float16 half8;
typedef __attribute__((ext_vector_type(4))) _Float16 half4v;

// ---------------------------------------------------------------------------
// Prep: clusters f32 [1024][512] -> wsB fp16, packed per K-step tile:
//   wsB[ks][c][32] (no swizzle — B is consumed via coalesced GLOBAL loads now,
//   each wave-load covers 16 rows x 64 B = 1 KiB contiguous).
// also computes c_sq[1024]. One wave per cluster.
// ---------------------------------------------------------------------------
__global__ __launch_bounds__(256) void prep_kernel(const float* __restrict__ clusters,
                                                   _Float16* __restrict__ wsB,
                                                   float* __restrict__ csq) {
    const int l  = threadIdx.x & 63;
    const int c  = (blockIdx.x << 2) + (threadIdx.x >> 6);   // cluster 0..1023
    const int ks = l >> 2;                                   // k-step 0..15
    const int j  = l & 3;                                    // 16B chunk 0..3

    const float* src = clusters + (size_t)c * DDIM + ks * BK + j * 8;
    floatx4 f0 = *(const floatx4*)src;
    floatx4 f1 = *(const floatx4*)(src + 4);

    half8 h;
    h[0] = (_Float16)f0[0]; h[1] = (_Float16)f0[1]; h[2] = (_Float16)f0[2]; h[3] = (_Float16)f0[3];
    h[4] = (_Float16)f1[0]; h[5] = (_Float16)f1[1]; h[6] = (_Float16)f1[2]; h[7] = (_Float16)f1[3];

    *(half8*)(wsB + (size_t)ks * (KCL * BK) + c * BK + j * 8) = h;

    float ss = f0[0]*f0[0] + f0[1]*f0[1] + f0[2]*f0[2] + f0[3]*f0[3]
             + f1[0]*f1[0] + f1[1]*f1[1] + f1[2]*f1[2] + f1[3]*f1[3];
    ss += __shfl_xor(ss, 1,  64);
    ss += __shfl_xor(ss, 2,  64);
    ss += __shfl_xor(ss, 4,  64);
    ss += __shfl_xor(ss, 8,  64);
    ss += __shfl_xor(ss, 16, 64);
    ss += __shfl_xor(ss, 32, 64);
    if (l == 0) csq[c] = ss;
}

// ---------------------------------------------------------------------------
// Main: one block = 64 rows x all 1024 clusters. 16 waves, wave w owns cols
// w*64..w*64+63 as 4(row) x 4(col) tiles of mfma_f32_16x16x32_f16.
//
// Structure (R2): A panel staged to LDS ONCE (65 KiB fp16), xsq computed
// during staging, single barrier. K-loop is BARRIER-FREE: B fragments come
// straight from L2 (wsB = 1 MiB, L2-resident) via coalesced dwordx4 loads
// with a 1-deep register ping-pong (bA/bB). No per-step vmcnt(0) drain —
// that drain was the R1 bottleneck (6.4K cyc/step vs ~1.2K of work).
// ---------------------------------------------------------------------------
__global__ __launch_bounds__(THR, 4)
void cluster_kernel(const float* __restrict__ x,
                    const _Float16* __restrict__ wsB,
                    const float* __restrict__ csq,
                    float* __restrict__ out) {
    extern __shared__ char smem[];
    char*  const sA     = smem;
    float* const xsq    = (float*)(smem + SA_BYTES);        // 64 f32
    float* const rowsum = (float*)(smem + SA_BYTES + 256);  // 64 f32

    const int t      = threadIdx.x;
    const int l      = t & 63;
    const int w      = t >> 6;          // 0..15
    const int lane16 = l & 15;
    const int kgrp   = l >> 4;          // 0..3
    const int row0   = blockIdx.x * RPB;
    const int wcol   = w << 6;          // wave's first column (64-wide slice)

    if (t < 64) { xsq[t] = 0.f; rowsum[t] = 0.f; }
    __syncthreads();

    // ---- stage entire A panel (64 x 512 f32 -> fp16 LDS), fold in xsq
    {
#pragma unroll
        for (int it = 0; it < 8; ++it) {
            const int g   = it * THR + t;       // float4-chunk index 0..8191
            const int row = g >> 7;             // block-local row (all 64 lanes of a wave share it)
            const int c4  = g & 127;            // float4 chunk within row
            floatx4 f = __builtin_nontemporal_load(
                (const floatx4*)(x + (size_t)(row0 + row) * DDIM + c4 * 4));
            half4v h;
            h[0] = (_Float16)f[0]; h[1] = (_Float16)f[1];
            h[2] = (_Float16)f[2]; h[3] = (_Float16)f[3];
            *(half4v*)(sA + row * SA_ROW_B + c4 * 8) = h;
            float ss = f[0]*f[0] + f[1]*f[1] + f[2]*f[2] + f[3]*f[3];
            ss += __shfl_xor(ss, 1,  64);
            ss += __shfl_xor(ss, 2,  64);
            ss += __shfl_xor(ss, 4,  64);
            ss += __shfl_xor(ss, 8,  64);
            ss += __shfl_xor(ss, 16, 64);
            ss += __shfl_xor(ss, 32, 64);
            if (l == 0) atomicAdd(&xsq[row], ss);
        }
    }
    __syncthreads();   // the ONLY barrier before the epilogue

    // fragment addresses
    const int abase = lane16 * SA_ROW_B + kgrp * 16;               // + k*64 + rt*16*SA_ROW_B
    const _Float16* const bbase = wsB + (size_t)(wcol + lane16) * BK + kgrp * 8;
    // loadB(ks, ct): bbase + ks*32768 + ct*512  (halves); per-wave 1 KiB contiguous per ct

    floatx4 acc[4][4];
#pragma unroll
    for (int rt = 0; rt < 4; ++rt)
#pragma unroll
        for (int ct = 0; ct < 4; ++ct)
            acc[rt][ct] = (floatx4){0.f, 0.f, 0.f, 0.f};

    half8 bA[4], bB[4];
#pragma unroll
    for (int ct = 0; ct < 4; ++ct)
        bA[ct] = *(const half8*)(bbase + ct * 512);

#define LOADB(dst, ks_)                                                        \
    _Pragma("unroll")                                                          \
    for (int ct = 0; ct < 4; ++ct)                                             \
        dst[ct] = *(const half8*)(bbase + (size_t)(ks_) * (KCL * BK) + ct * 512);

#define COMPUTE(k_, bsrc)                                                      \
    {                                                                          \
        half8 aF[4];                                                           \
        _Pragma("unroll")                                                      \
        for (int rt = 0; rt < 4; ++rt)                                         \
            aF[rt] = *(const half8*)(sA + abase + (k_) * 64 + rt * (16 * SA_ROW_B)); \
        _Pragma("unroll")                                                      \
        for (int ct = 0; ct < 4; ++ct)                                         \
            _Pragma("unroll")                                                  \
            for (int rt = 0; rt < 4; ++rt)                                     \
                acc[rt][ct] = __builtin_amdgcn_mfma_f32_16x16x32_f16(          \
                    aF[rt], bsrc[ct], acc[rt][ct], 0, 0, 0);                   \
    }

#pragma unroll
    for (int kk = 0; kk < KSTEPS; kk += 2) {
        if (kk + 1 < KSTEPS) LOADB(bB, kk + 1);   // prefetch for step kk+1
        COMPUTE(kk, bA);
        if (kk + 2 < KSTEPS) LOADB(bA, kk + 2);   // prefetch for step kk+2
        if (kk + 1 < KSTEPS) COMPUTE(kk + 1, bB);
    }
#undef LOADB
#undef COMPUTE

    // ---- epilogue. C layout: col = lane&15, row = (lane>>4)*4 + reg (m89/m91)
    float cs[4];
#pragma unroll
    for (int ct = 0; ct < 4; ++ct)
        cs[ct] = csq[wcol + ct * 16 + lane16];
    floatx4 xv[4];
#pragma unroll
    for (int rt = 0; rt < 4; ++rt)
        xv[rt] = *(const floatx4*)(xsq + rt * 16 + kgrp * 4);

    float rp[4][4];
#pragma unroll
    for (int rt = 0; rt < 4; ++rt) {
#pragma unroll
        for (int i = 0; i < 4; ++i) {
            const float xr = xv[rt][i];
            float s = 0.f;
#pragma unroll
            for (int ct = 0; ct < 4; ++ct) {
                float d = xr + cs[ct] - 2.0f * acc[rt][ct][i];
                d = fmaxf(d, 0.0f);
                const float q = __builtin_amdgcn_rcpf(1.0f + d);   // ALPHA=1 -> exponent 1
                acc[rt][ct][i] = q;
                s += q;
            }
            rp[rt][i] = s;
        }
    }
    // reduce partial row sums across the 16 lanes sharing kgrp
#pragma unroll
    for (int m = 1; m <= 8; m <<= 1)
#pragma unroll
        for (int rt = 0; rt < 4; ++rt)
#pragma unroll
            for (int i = 0; i < 4; ++i)
                rp[rt][i] += __shfl_xor(rp[rt][i], m, 64);
    if (lane16 == 0) {
#pragma unroll
        for (int rt = 0; rt < 4; ++rt)
#pragma unroll
            for (int i = 0; i < 4; ++i)
                atomicAdd(&rowsum[rt * 16 + kgrp * 4 + i], rp[rt][i]);
    }
    __syncthreads();

    // plain (cached) stores: L2 merges the 64B lane-group quadrants into lines
#pragma unroll
    for (int rt = 0; rt < 4; ++rt) {
        const floatx4 rs = *(const floatx4*)(rowsum + rt * 16 + kgrp * 4);
#pragma unroll
        for (int i = 0; i < 4; ++i) {
            const float inv = __builtin_amdgcn_rcpf(rs[i]);
            float* orow = out + (size_t)(row0 + rt * 16 + kgrp * 4 + i) * KCL + wcol + lane16;
#pragma unroll
            for (int ct = 0; ct < 4; ++ct)
                orow[ct * 16] = acc[rt][ct][i] * inv;
        }
    }
}

extern "C" void kernel_launch(void* const* d_in, const int* in_sizes, int n_in,
                              void* d_out, int out_size, void* d_ws, size_t ws_size,
                              hipStream_t stream) {
    (void)in_sizes; (void)n_in; (void)out_size; (void)ws_size;
    const float* x        = (const float*)d_in[0];
    const float* clusters = (const float*)d_in[1];
    float* out = (float*)d_out;

    _Float16* wsB = (_Float16*)d_ws;                                   // 1 MiB packed fp16 B
    float*    csq = (float*)((char*)d_ws + (size_t)KSTEPS * KCL * BK * 2);  // 4 KiB

    hipFuncSetAttribute((const void*)cluster_kernel,
                        hipFuncAttributeMaxDynamicSharedMemorySize, SMEM_BYTES);

    prep_kernel<<<KCL / 4, 256, 0, stream>>>(clusters, wsB, csq);
    cluster_kernel<<<NBLK, THR, SMEM_BYTES, stream>>>(x, wsB, csq, out);
}